// Round 10
// baseline (257.709 us; speedup 1.0000x reference)
//
#include <hip/hip_runtime.h>
#include <hip/hip_bf16.h>

#define N_NODES 100000
#define N_EDGES 1000000
#define EMB 64
#define HID 64
#define VOCAB 128
#define N_GRAPHS 2048

#define CBUCKET 1024                                   // nodes per bucket
#define NBK ((N_NODES + CBUCKET - 1) / CBUCKET)        // 98
#define CAP 16384                                      // slots per bucket (E[cnt]=10204)
#define CHUNK 4096
#define SCAT_BLOCKS ((N_EDGES + CHUNK - 1) / CHUNK)    // 245

#define BCASTF(v, l) __int_as_float(__builtin_amdgcn_readlane(__float_as_int(v), (l)))

typedef __attribute__((ext_vector_type(8))) short short8;
typedef __attribute__((ext_vector_type(4))) float f32x4;

__device__ __forceinline__ float bf2f(unsigned short u) {
    return __uint_as_float((unsigned)u << 16);
}
__device__ __forceinline__ unsigned short f2bf(float f) {
    return __bfloat16_as_ushort(__float2bfloat16(f));
}

// ---- init: cursor[k] = k*CAP, gsum = 0 ----
__global__ __launch_bounds__(256) void init_kernel(
    int* __restrict__ cursor, float* __restrict__ gsum)
{
    int t = blockIdx.x * 256 + threadIdx.x;
    if (t < NBK) cursor[t] = t * CAP;
    if (t < N_GRAPHS * 2) gsum[t] = 0.f;
}

// ---- precompute embW1l = emb@W1l, embW1r = emb@W1r (128x64 fp32)
//      + pack W2cat = [W2l | W2r] (64x128) into MFMA B-fragment order bf16.
__global__ __launch_bounds__(256) void precompute_kernel(
    const float* __restrict__ emb, const float* __restrict__ W1l,
    const float* __restrict__ W1r,
    const float* __restrict__ W2l, const float* __restrict__ W2r,
    float* __restrict__ embW1l, float* __restrict__ embW1r,
    unsigned short* __restrict__ w2frag)
{
    int wave = threadIdx.x >> 6, lane = threadIdx.x & 63;
    int v = blockIdx.x * 4 + wave;
    if (v < VOCAB) {
        float er = emb[v * 64 + lane];       // lane = d
        float al = 0.f, ar = 0.f;
#pragma unroll 8
        for (int d = 0; d < 64; ++d) {
            float e = BCASTF(er, d);
            al += e * W1l[d * 64 + lane];    // lane = o, L1-hot
            ar += e * W1r[d * 64 + lane];
        }
        embW1l[v * 64 + lane] = al;
        embW1r[v * 64 + lane] = ar;
    }
    // B-fragment packing: g = t*1024 + h*512 + l*8 + j
    int g = blockIdx.x * 256 + threadIdx.x;
    int j = g & 7, l = (g >> 3) & 63, h = (g >> 9) & 1, tt = g >> 10;
    int k = h * 32 + ((l >> 4) * 8) + j;
    int n = tt * 16 + (l & 15);
    float w = (n < 64) ? W2l[k * 64 + n] : W2r[k * 64 + (n - 64)];
    w2frag[g] = f2bf(w);
}

// ---- scatter: LDS-staged chunk, per-(block,bucket) run reservation ----
__global__ __launch_bounds__(256) void scatter_kernel(
    const int* __restrict__ src, const int* __restrict__ dst,
    int* __restrict__ cursor, unsigned* __restrict__ edge8)
{
    __shared__ unsigned earr[CHUNK];        // 16 KB packed payload
    __shared__ unsigned char karr[CHUNK];   // 4 KB bucket key
    __shared__ int bcnt[NBK];
    __shared__ int bbase[NBK];
    int t = threadIdx.x;
    if (t < NBK) bcnt[t] = 0;
    __syncthreads();
    int e0 = blockIdx.x * CHUNK;
    int n = min(e0 + CHUNK, N_EDGES) - e0;
    for (int i = t; i < n; i += 256) {
        int d = dst[e0 + i];
        int s = src[e0 + i];
        int k = d >> 10;
        earr[i] = (unsigned)s | ((unsigned)(d & 1023) << 17);   // src < 2^17
        karr[i] = (unsigned char)k;
        atomicAdd(&bcnt[k], 1);
    }
    __syncthreads();
    if (t < NBK) {
        int c = bcnt[t];
        bbase[t] = c ? atomicAdd(&cursor[t], c) : 0;
        bcnt[t] = 0;                        // reuse as local cursor
    }
    __syncthreads();
    for (int i = t; i < n; i += 256) {
        int k = karr[i];
        int off = atomicAdd(&bcnt[k], 1);
        edge8[bbase[k] + off] = earr[i];    // dense single-writer runs
    }
}

// ---- per-bucket CSR build (rowstart/deg/col), dense writes ------
__global__ __launch_bounds__(256) void csr_kernel(
    const unsigned* __restrict__ edge8, const int* __restrict__ cursor,
    int* __restrict__ row_start, int* __restrict__ deg, int* __restrict__ col)
{
    __shared__ int cnt[CBUCKET];
    __shared__ int ssum[256];
    int b = blockIdx.x;                   // NBK blocks
    int t = threadIdx.x;
    int lo = b * CAP, hi = cursor[b];     // cursor holds final fill level
    for (int i = t; i < CBUCKET; i += 256) cnt[i] = 0;
    __syncthreads();
    for (int i = lo + t; i < hi; i += 256)
        atomicAdd(&cnt[edge8[i] >> 17], 1);
    __syncthreads();
    int v[4]; int sum = 0;
#pragma unroll
    for (int i = 0; i < 4; ++i) { v[i] = cnt[t * 4 + i]; sum += v[i]; }
    ssum[t] = sum;
    __syncthreads();
    for (int off = 1; off < 256; off <<= 1) {
        int tmp = (t >= off) ? ssum[t - off] : 0;
        __syncthreads();
        ssum[t] += tmp;
        __syncthreads();
    }
    int run = ssum[t] - sum;
    int ex0 = run, ex1 = ex0 + v[0], ex2 = ex1 + v[1], ex3 = ex2 + v[2];
    int node = b * CBUCKET + t * 4;
    if (node + 3 < N_NODES) {
        *(int4*)&row_start[node] = make_int4(lo + ex0, lo + ex1, lo + ex2, lo + ex3);
        *(int4*)&deg[node]       = make_int4(v[0], v[1], v[2], v[3]);
    } else {
        int ex[4] = {ex0, ex1, ex2, ex3};
        for (int i = 0; i < 4; ++i)
            if (node + i < N_NODES) { row_start[node + i] = lo + ex[i]; deg[node + i] = v[i]; }
    }
    cnt[t * 4 + 0] = ex0; cnt[t * 4 + 1] = ex1;       // reuse as cursors
    cnt[t * 4 + 2] = ex2; cnt[t * 4 + 3] = ex3;
    __syncthreads();
    for (int i = lo + t; i < hi; i += 256) {
        unsigned e = edge8[i];
        int slot = atomicAdd(&cnt[e >> 17], 1);
        col[lo + slot] = (int)(e & 0x1FFFF);          // dense ~40 KB window
    }
}

// ---- graph boundaries (batch sorted) -------------------------------------
__global__ __launch_bounds__(256) void gstart_kernel(
    const int* __restrict__ batch, int* __restrict__ gstart)
{
    int i = blockIdx.x * 256 + threadIdx.x;
    if (i >= N_NODES) return;
    int bg = batch[i];
    int bp = (i == 0) ? -1 : batch[i - 1];
    for (int g = bp + 1; g <= bg; ++g) gstart[g] = i;
    if (i == N_NODES - 1)
        for (int g = bg + 1; g <= N_GRAPHS; ++g) gstart[g] = N_NODES;
}

// ---- layer 1 (lean): h1 = relu(mean_j(embW1l[x_j]) + b1 + embW1r[x_i]) ----
#define S1_NPW 8
__global__ __launch_bounds__(256) void sage1_kernel(
    const int* __restrict__ x, const float* __restrict__ embW1l,
    const float* __restrict__ embW1r, const float* __restrict__ b1,
    const int* __restrict__ row_start, const int* __restrict__ deg,
    const int* __restrict__ col, unsigned short* __restrict__ h1b)
{
    __shared__ float elds[VOCAB * 64];      // 32 KB -> 5 blocks/CU
    int t = threadIdx.x;
    for (int i = t * 4; i < VOCAB * 64; i += 1024)
        *(float4*)&elds[i] = *(const float4*)&embW1l[i];
    __syncthreads();

    int wave = t >> 6, lane = t & 63;
    int base_node = (blockIdx.x * 4 + wave) * S1_NPW;   // 3125*32 = 100000 exact
    float bias = b1[lane];

    int rs[S1_NPW], dgs[S1_NPW], cidx[S1_NPW], xv[S1_NPW], xn[S1_NPW];
    float self[S1_NPW];
#pragma unroll
    for (int n = 0; n < S1_NPW; ++n) {
        rs[n] = row_start[base_node + n];
        dgs[n] = deg[base_node + n];
        xn[n] = x[base_node + n];
    }
#pragma unroll
    for (int n = 0; n < S1_NPW; ++n)
        cidx[n] = (lane < dgs[n]) ? col[rs[n] + lane] : 0;
#pragma unroll
    for (int n = 0; n < S1_NPW; ++n) {
        xv[n] = (lane < dgs[n]) ? x[cidx[n]] : 0;
        self[n] = embW1r[xn[n] * 64 + lane];
    }

    for (int n = 0; n < S1_NPW; ++n) {
        int node = base_node + n;
        int dg = dgs[n];
        int dgc = (dg < 64) ? dg : 64;

        float s0 = 0.f, s1 = 0.f, s2 = 0.f, s3 = 0.f;
        int j = 0;
        for (; j + 4 <= dgc; j += 4) {
            int x0 = __builtin_amdgcn_readlane(xv[n], j + 0);
            int x1 = __builtin_amdgcn_readlane(xv[n], j + 1);
            int x2 = __builtin_amdgcn_readlane(xv[n], j + 2);
            int x3 = __builtin_amdgcn_readlane(xv[n], j + 3);
            s0 += elds[x0 * 64 + lane];
            s1 += elds[x1 * 64 + lane];
            s2 += elds[x2 * 64 + lane];
            s3 += elds[x3 * 64 + lane];
        }
        for (; j < dgc; ++j) {
            int x0 = __builtin_amdgcn_readlane(xv[n], j);
            s0 += elds[x0 * 64 + lane];
        }
        for (int k = 64; k < dg; ++k) {                 // deg>64 tail (rare)
            int c = col[rs[n] + k];
            s0 += elds[x[c] * 64 + lane];
        }
        float mean = ((s0 + s1) + (s2 + s3)) / fmaxf((float)dg, 1.0f);
        h1b[node * 64 + lane] = f2bf(fmaxf(mean + bias + self[n], 0.f));
    }
}

// ---- MFMA transform: [p|q] = h1 @ [W2l|W2r]  (M=100000, N=128, K=64) ----
__global__ __launch_bounds__(256) void mfma_transform_kernel(
    const unsigned short* __restrict__ h1b,
    const unsigned short* __restrict__ w2frag,
    unsigned short* __restrict__ p16, unsigned short* __restrict__ q16)
{
    int wave = threadIdx.x >> 6, lane = threadIdx.x & 63;
    int base16 = blockIdx.x * 64 + wave * 16;
    if (base16 >= N_NODES) return;                      // tail waves only
    int m = lane & 15, quad = lane >> 4;

    const unsigned short* arow = h1b + (base16 + m) * 64 + quad * 8;
    short8 a0 = *(const short8*)(arow);                 // k = 0..31
    short8 a1 = *(const short8*)(arow + 32);            // k = 32..63

#pragma unroll
    for (int tt = 0; tt < 8; ++tt) {                    // 8 output tiles of 16
        short8 b0 = *(const short8*)(w2frag + (tt * 1024 + 0)   + lane * 8);
        short8 b1 = *(const short8*)(w2frag + (tt * 1024 + 512) + lane * 8);
        f32x4 acc = {0.f, 0.f, 0.f, 0.f};
        acc = __builtin_amdgcn_mfma_f32_16x16x32_bf16(a0, b0, acc, 0, 0, 0);
        acc = __builtin_amdgcn_mfma_f32_16x16x32_bf16(a1, b1, acc, 0, 0, 0);
        int o = tt * 16 + m;
        unsigned short* dstbuf = (o < 64) ? p16 : q16;
        int oc = o & 63;
#pragma unroll
        for (int i = 0; i < 4; ++i) {
            int node = base16 + quad * 4 + i;
            dstbuf[node * 64 + oc] = f2bf(acc[i]);
        }
    }
}

// ---- gather v4: CSR edge-walk, explicit 16-deep load pipeline -------------
// One wave per 32 consecutive nodes (contiguous edge range in col).
// lane = feature. All control flow is wave-uniform scalar.
#define PIPE 16
#define S2G 32

#define S2_FLUSH() do {                                                     \
    float dgf = (float)__builtin_amdgcn_readlane(dg_l, cur);                \
    float mean = acc / fmaxf(dgf, 1.0f);                                    \
    float h2 = fmaxf(mean + b2v + bf2f(qc), 0.f);                           \
    float r0 = h2 * wo0, r1 = h2 * wo1;                                     \
    r0 += __shfl_xor(r0, 1, 64);  r1 += __shfl_xor(r1, 1, 64);              \
    r0 += __shfl_xor(r0, 2, 64);  r1 += __shfl_xor(r1, 2, 64);              \
    r0 += __shfl_xor(r0, 4, 64);  r1 += __shfl_xor(r1, 4, 64);              \
    r0 += __shfl_xor(r0, 8, 64);  r1 += __shfl_xor(r1, 8, 64);              \
    r0 += __shfl_xor(r0, 16, 64); r1 += __shfl_xor(r1, 16, 64);             \
    r0 += __shfl_xor(r0, 32, 64); r1 += __shfl_xor(r1, 32, 64);             \
    int grp = __builtin_amdgcn_readlane(bid_l, cur);                        \
    if (lane == 0) {                                                        \
        atomicAdd(&gsum[grp * 2 + 0], r0);                                  \
        atomicAdd(&gsum[grp * 2 + 1], r1);                                  \
    }                                                                       \
    acc = 0.f;                                                              \
    cur++;                                                                  \
    qc = qn;                                                                \
    if (cur + 1 < S2G) qn = q[(n0 + cur + 1) * 64 + lane];                  \
    if (cur < S2G) nb += __builtin_amdgcn_readlane(dg_l, cur);              \
} while (0)

__global__ __launch_bounds__(256, 8) void sage2_kernel(
    const unsigned short* __restrict__ p, const unsigned short* __restrict__ q,
    const int* __restrict__ row_start, const int* __restrict__ deg,
    const int* __restrict__ col, const float* __restrict__ b2,
    const float* __restrict__ Wout, const int* __restrict__ batch,
    float* __restrict__ gsum)
{
    int t = threadIdx.x;
    int wave = t >> 6, lane = t & 63;
    int n0 = (blockIdx.x * 4 + wave) * S2G;
    if (n0 >= N_NODES) return;                          // 3125 waves exact

    int nl = n0 + (lane & 31);                          // lanes 0..31 hold node meta
    int rs_l = row_start[nl];
    int dg_l = deg[nl];
    int bid_l = batch[nl];

    float b2v = b2[lane];
    float wo0 = Wout[lane * 2 + 0], wo1 = Wout[lane * 2 + 1];

    int e_beg = __builtin_amdgcn_readfirstlane(rs_l);
    int e_end = __builtin_amdgcn_readlane(rs_l, 31) + __builtin_amdgcn_readlane(dg_l, 31);

    // col double-batch window [hb, hb+128)
    int hb = e_beg;
    int colA = col[hb + lane];
    int colB = col[hb + 64 + lane];

    // prologue: issue PIPE loads (junk beyond e_end never consumed; & mask
    // keeps poisoned col slots inside the workspace)
    unsigned short rowreg[PIPE];
#pragma unroll
    for (int k = 0; k < PIPE; ++k) {
        int s = __builtin_amdgcn_readlane(colA, k) & 0x1FFFF;
        rowreg[k] = p[s * 64 + lane];
    }

    int cur = 0;
    int nb = e_beg + __builtin_amdgcn_readlane(dg_l, 0);
    unsigned short qc = q[n0 * 64 + lane];
    unsigned short qn = q[(n0 + 1) * 64 + lane];
    float acc = 0.f;
    int ei = e_beg;

    while (ei + PIPE <= e_end) {
        while (ei - hb >= 64) {                         // rotate col window
            colA = colB;
            colB = col[hb + 128 + lane];
            hb += 64;
        }
#pragma unroll
        for (int k = 0; k < PIPE; ++k) {
            while (cur < S2G && ei == nb) S2_FLUSH();
            acc += bf2f(rowreg[k]);                     // waits oldest load only
            int slot = ei + PIPE - hb;                  // uniform, < 128
            int s = ((slot < 64) ? __builtin_amdgcn_readlane(colA, slot)
                                 : __builtin_amdgcn_readlane(colB, slot - 64)) & 0x1FFFF;
            rowreg[k] = p[s * 64 + lane];               // reissue slot k
            ++ei;
        }
    }
    {   // tail: < PIPE edges remain; slot of edge ei+k is exactly k
        int rem = e_end - ei;
#pragma unroll
        for (int k = 0; k < PIPE; ++k) {
            if (k < rem) {
                while (cur < S2G && ei == nb) S2_FLUSH();
                acc += bf2f(rowreg[k]);
                ++ei;
            }
        }
    }
    while (cur < S2G) S2_FLUSH();                       // incl. trailing deg-0 nodes
}

// ---------------- finalize: out = gsum/cnt + bout ----------------
__global__ __launch_bounds__(256) void finalize_kernel(
    const float* __restrict__ gsum, const int* __restrict__ gstart,
    const float* __restrict__ bout, float* __restrict__ out)
{
    int g = blockIdx.x * 256 + threadIdx.x;
    if (g >= N_GRAPHS) return;
    int cnt = gstart[g + 1] - gstart[g];
    float inv = 1.0f / fmaxf((float)cnt, 1.0f);
    out[g * 2 + 0] = gsum[g * 2 + 0] * inv + bout[0];
    out[g * 2 + 1] = gsum[g * 2 + 1] * inv + bout[1];
}

extern "C" void kernel_launch(void* const* d_in, const int* in_sizes, int n_in,
                              void* d_out, int out_size, void* d_ws, size_t ws_size,
                              hipStream_t stream) {
    const int*   x    = (const int*)  d_in[0];
    const int*   ei   = (const int*)  d_in[1];
    const int*   batch= (const int*)  d_in[2];
    const float* emb  = (const float*)d_in[3];
    const float* W1l  = (const float*)d_in[4];
    const float* b1   = (const float*)d_in[5];
    const float* W1r  = (const float*)d_in[6];
    const float* W2l  = (const float*)d_in[7];
    const float* b2   = (const float*)d_in[8];
    const float* W2r  = (const float*)d_in[9];
    const float* Wout = (const float*)d_in[10];
    const float* bout = (const float*)d_in[11];
    float* out = (float*)d_out;

    const int* src = ei;
    const int* dst = ei + N_EDGES;

    char* ws = (char*)d_ws;
    size_t off = 0;
    unsigned short* p16    = (unsigned short*)(ws + off); off += (size_t)N_NODES * 64 * 2;
    unsigned short* q16    = (unsigned short*)(ws + off); off += (size_t)N_NODES * 64 * 2;
    unsigned short* h1b    = (unsigned short*)(ws + off); off += (size_t)N_NODES * 64 * 2;
    unsigned short* w2frag = (unsigned short*)(ws + off); off += (size_t)8192 * 2;
    float*    embW1l = (float*)   (ws + off); off += (size_t)VOCAB * 64 * 4;
    float*    embW1r = (float*)   (ws + off); off += (size_t)VOCAB * 64 * 4;
    int*      rowst  = (int*)     (ws + off); off += (size_t)N_NODES * 4;
    int*      deg    = (int*)     (ws + off); off += (size_t)N_NODES * 4;
    int*      col    = (int*)     (ws + off); off += (size_t)(NBK * CAP + 256) * 4; // +pad for window reads
    unsigned* edge8  = (unsigned*)(ws + off); off += (size_t)NBK * CAP * 4;
    int*      cursor = (int*)     (ws + off); off += (size_t)NBK * 4;
    int*      gstart = (int*)     (ws + off); off += (size_t)(N_GRAPHS + 1) * 4;
    float*    gsum   = (float*)   (ws + off); off += (size_t)N_GRAPHS * 2 * 4;

    init_kernel<<<16, 256, 0, stream>>>(cursor, gsum);
    precompute_kernel<<<32, 256, 0, stream>>>(emb, W1l, W1r, W2l, W2r,
                                              embW1l, embW1r, w2frag);
    scatter_kernel<<<SCAT_BLOCKS, 256, 0, stream>>>(src, dst, cursor, edge8);
    gstart_kernel<<<(N_NODES + 255) / 256, 256, 0, stream>>>(batch, gstart);
    csr_kernel<<<NBK, 256, 0, stream>>>(edge8, cursor, rowst, deg, col);
    sage1_kernel<<<N_NODES / (4 * S1_NPW), 256, 0, stream>>>(
        x, embW1l, embW1r, b1, rowst, deg, col, h1b);
    mfma_transform_kernel<<<(N_NODES + 63) / 64, 256, 0, stream>>>(
        h1b, w2frag, p16, q16);
    sage2_kernel<<<(N_NODES / (4 * S2G)) + 1, 256, 0, stream>>>(
        p16, q16, rowst, deg, col, b2, Wout, batch, gsum);
    finalize_kernel<<<(N_GRAPHS + 255) / 256, 256, 0, stream>>>(gsum, gstart, bout, out);
}

// Round 11
// 227.866 us; speedup vs baseline: 1.1310x; 1.1310x over previous
//
#include <hip/hip_runtime.h>
#include <hip/hip_bf16.h>

#define N_NODES 100000
#define N_EDGES 1000000
#define EMB 64
#define HID 64
#define VOCAB 128
#define N_GRAPHS 2048

#define CBUCKET 1024                                   // nodes per bucket
#define NBK ((N_NODES + CBUCKET - 1) / CBUCKET)        // 98
#define CAP 16384                                      // slots per bucket (E[cnt]=10204)
#define CHUNK 4096
#define SCAT_BLOCKS ((N_EDGES + CHUNK - 1) / CHUNK)    // 245
#define GB ((N_NODES + 255) / 256)                     // 391 gstart blocks

#define BCASTF(v, l) __int_as_float(__builtin_amdgcn_readlane(__float_as_int(v), (l)))

typedef __attribute__((ext_vector_type(8))) short short8;
typedef __attribute__((ext_vector_type(4))) float f32x4;

__device__ __forceinline__ float bf2f(unsigned short u) {
    return __uint_as_float((unsigned)u << 16);
}
__device__ __forceinline__ unsigned short f2bf(float f) {
    return __bfloat16_as_ushort(__float2bfloat16(f));
}

// ---- fused setup: gstart (blocks 0..GB-1) + precompute (GB..GB+31) + init --
__global__ __launch_bounds__(256) void setup_kernel(
    const int* __restrict__ batch, int* __restrict__ gstart,
    const float* __restrict__ emb, const float* __restrict__ W1l,
    const float* __restrict__ W1r,
    const float* __restrict__ W2l, const float* __restrict__ W2r,
    float* __restrict__ embW1l, float* __restrict__ embW1r,
    unsigned short* __restrict__ w2frag,
    int* __restrict__ cursor, float* __restrict__ gsum)
{
    int b = blockIdx.x;
    int t = threadIdx.x;
    if (b < GB) {
        // graph boundaries (batch sorted)
        int i = b * 256 + t;
        if (i >= N_NODES) return;
        int bg = batch[i];
        int bp = (i == 0) ? -1 : batch[i - 1];
        for (int g = bp + 1; g <= bg; ++g) gstart[g] = i;
        if (i == N_NODES - 1)
            for (int g = bg + 1; g <= N_GRAPHS; ++g) gstart[g] = N_NODES;
    } else if (b < GB + 32) {
        int vb = b - GB;
        int wave = t >> 6, lane = t & 63;
        int v = vb * 4 + wave;
        if (v < VOCAB) {
            float er = emb[v * 64 + lane];       // lane = d
            float al = 0.f, ar = 0.f;
#pragma unroll 8
            for (int d = 0; d < 64; ++d) {
                float e = BCASTF(er, d);
                al += e * W1l[d * 64 + lane];
                ar += e * W1r[d * 64 + lane];
            }
            embW1l[v * 64 + lane] = al;
            embW1r[v * 64 + lane] = ar;
        }
        // W2 B-fragment packing: g = tt*1024 + h*512 + l*8 + j
        int g = vb * 256 + t;
        int j = g & 7, l = (g >> 3) & 63, h = (g >> 9) & 1, tt = g >> 10;
        int k = h * 32 + ((l >> 4) * 8) + j;
        int n = tt * 16 + (l & 15);
        float w = (n < 64) ? W2l[k * 64 + n] : W2r[k * 64 + (n - 64)];
        w2frag[g] = f2bf(w);
    } else {
        if (t < NBK) cursor[t] = t * CAP;
        for (int i = t; i < N_GRAPHS * 2; i += 256) gsum[i] = 0.f;
    }
}

// ---- scatter: LDS-staged chunk, per-(block,bucket) run reservation ----
__global__ __launch_bounds__(256) void scatter_kernel(
    const int* __restrict__ src, const int* __restrict__ dst,
    int* __restrict__ cursor, unsigned* __restrict__ edge8)
{
    __shared__ unsigned earr[CHUNK];        // 16 KB packed payload
    __shared__ unsigned char karr[CHUNK];   // 4 KB bucket key
    __shared__ int bcnt[NBK];
    __shared__ int bbase[NBK];
    int t = threadIdx.x;
    if (t < NBK) bcnt[t] = 0;
    __syncthreads();
    int e0 = blockIdx.x * CHUNK;
    int n = min(e0 + CHUNK, N_EDGES) - e0;
    for (int i = t; i < n; i += 256) {
        int d = dst[e0 + i];
        int s = src[e0 + i];
        int k = d >> 10;
        earr[i] = (unsigned)s | ((unsigned)(d & 1023) << 17);   // src < 2^17
        karr[i] = (unsigned char)k;
        atomicAdd(&bcnt[k], 1);
    }
    __syncthreads();
    if (t < NBK) {
        int c = bcnt[t];
        bbase[t] = c ? atomicAdd(&cursor[t], c) : 0;
        bcnt[t] = 0;                        // reuse as local cursor
    }
    __syncthreads();
    for (int i = t; i < n; i += 256) {
        int k = karr[i];
        int off = atomicAdd(&bcnt[k], 1);
        edge8[bbase[k] + off] = earr[i];    // dense single-writer runs
    }
}

// ---- per-bucket CSR build (rowstart/deg/col), dense writes ------
__global__ __launch_bounds__(256) void csr_kernel(
    const unsigned* __restrict__ edge8, const int* __restrict__ cursor,
    int* __restrict__ row_start, int* __restrict__ deg, int* __restrict__ col)
{
    __shared__ int cnt[CBUCKET];
    __shared__ int ssum[256];
    int b = blockIdx.x;                   // NBK blocks
    int t = threadIdx.x;
    int lo = b * CAP, hi = cursor[b];     // cursor holds final fill level
    for (int i = t; i < CBUCKET; i += 256) cnt[i] = 0;
    __syncthreads();
    for (int i = lo + t; i < hi; i += 256)
        atomicAdd(&cnt[edge8[i] >> 17], 1);
    __syncthreads();
    int v[4]; int sum = 0;
#pragma unroll
    for (int i = 0; i < 4; ++i) { v[i] = cnt[t * 4 + i]; sum += v[i]; }
    ssum[t] = sum;
    __syncthreads();
    for (int off = 1; off < 256; off <<= 1) {
        int tmp = (t >= off) ? ssum[t - off] : 0;
        __syncthreads();
        ssum[t] += tmp;
        __syncthreads();
    }
    int run = ssum[t] - sum;
    int ex0 = run, ex1 = ex0 + v[0], ex2 = ex1 + v[1], ex3 = ex2 + v[2];
    int node = b * CBUCKET + t * 4;
    if (node + 3 < N_NODES) {
        *(int4*)&row_start[node] = make_int4(lo + ex0, lo + ex1, lo + ex2, lo + ex3);
        *(int4*)&deg[node]       = make_int4(v[0], v[1], v[2], v[3]);
    } else {
        int ex[4] = {ex0, ex1, ex2, ex3};
        for (int i = 0; i < 4; ++i)
            if (node + i < N_NODES) { row_start[node + i] = lo + ex[i]; deg[node + i] = v[i]; }
    }
    cnt[t * 4 + 0] = ex0; cnt[t * 4 + 1] = ex1;       // reuse as cursors
    cnt[t * 4 + 2] = ex2; cnt[t * 4 + 3] = ex3;
    __syncthreads();
    for (int i = lo + t; i < hi; i += 256) {
        unsigned e = edge8[i];
        int slot = atomicAdd(&cnt[e >> 17], 1);
        col[lo + slot] = (int)(e & 0x1FFFF);          // dense ~40 KB window
    }
}

// ---- layer 1 (lean): h1 = relu(mean_j(embW1l[x_j]) + b1 + embW1r[x_i]) ----
#define S1_NPW 8
__global__ __launch_bounds__(256) void sage1_kernel(
    const int* __restrict__ x, const float* __restrict__ embW1l,
    const float* __restrict__ embW1r, const float* __restrict__ b1,
    const int* __restrict__ row_start, const int* __restrict__ deg,
    const int* __restrict__ col, unsigned short* __restrict__ h1b)
{
    __shared__ float elds[VOCAB * 64];      // 32 KB -> 5 blocks/CU
    int t = threadIdx.x;
    for (int i = t * 4; i < VOCAB * 64; i += 1024)
        *(float4*)&elds[i] = *(const float4*)&embW1l[i];
    __syncthreads();

    int wave = t >> 6, lane = t & 63;
    int base_node = (blockIdx.x * 4 + wave) * S1_NPW;   // 3125*32 = 100000 exact
    float bias = b1[lane];

    int rs[S1_NPW], dgs[S1_NPW], cidx[S1_NPW], xv[S1_NPW], xn[S1_NPW];
    float self[S1_NPW];
#pragma unroll
    for (int n = 0; n < S1_NPW; ++n) {
        rs[n] = row_start[base_node + n];
        dgs[n] = deg[base_node + n];
        xn[n] = x[base_node + n];
    }
#pragma unroll
    for (int n = 0; n < S1_NPW; ++n)
        cidx[n] = (lane < dgs[n]) ? col[rs[n] + lane] : 0;
#pragma unroll
    for (int n = 0; n < S1_NPW; ++n) {
        xv[n] = (lane < dgs[n]) ? x[cidx[n]] : 0;
        self[n] = embW1r[xn[n] * 64 + lane];
    }

    for (int n = 0; n < S1_NPW; ++n) {
        int node = base_node + n;
        int dg = dgs[n];
        int dgc = (dg < 64) ? dg : 64;

        float s0 = 0.f, s1 = 0.f, s2 = 0.f, s3 = 0.f;
        int j = 0;
        for (; j + 4 <= dgc; j += 4) {
            int x0 = __builtin_amdgcn_readlane(xv[n], j + 0);
            int x1 = __builtin_amdgcn_readlane(xv[n], j + 1);
            int x2 = __builtin_amdgcn_readlane(xv[n], j + 2);
            int x3 = __builtin_amdgcn_readlane(xv[n], j + 3);
            s0 += elds[x0 * 64 + lane];
            s1 += elds[x1 * 64 + lane];
            s2 += elds[x2 * 64 + lane];
            s3 += elds[x3 * 64 + lane];
        }
        for (; j < dgc; ++j) {
            int x0 = __builtin_amdgcn_readlane(xv[n], j);
            s0 += elds[x0 * 64 + lane];
        }
        for (int k = 64; k < dg; ++k) {                 // deg>64 tail (rare)
            int c = col[rs[n] + k];
            s0 += elds[x[c] * 64 + lane];
        }
        float mean = ((s0 + s1) + (s2 + s3)) / fmaxf((float)dg, 1.0f);
        h1b[node * 64 + lane] = f2bf(fmaxf(mean + bias + self[n], 0.f));
    }
}

// ---- MFMA transform: [p|q] = h1 @ [W2l|W2r]  (M=100000, N=128, K=64) ----
// p stored fp8 e4m3 (gathered later -> smaller working set), q stored bf16.
__global__ __launch_bounds__(256) void mfma_transform_kernel(
    const unsigned short* __restrict__ h1b,
    const unsigned short* __restrict__ w2frag,
    unsigned char* __restrict__ p8, unsigned short* __restrict__ q16)
{
    int wave = threadIdx.x >> 6, lane = threadIdx.x & 63;
    int base16 = blockIdx.x * 64 + wave * 16;
    if (base16 >= N_NODES) return;                      // tail waves only
    int m = lane & 15, quad = lane >> 4;

    const unsigned short* arow = h1b + (base16 + m) * 64 + quad * 8;
    short8 a0 = *(const short8*)(arow);                 // k = 0..31
    short8 a1 = *(const short8*)(arow + 32);            // k = 32..63

#pragma unroll
    for (int tt = 0; tt < 8; ++tt) {                    // 8 output tiles of 16
        short8 b0 = *(const short8*)(w2frag + (tt * 1024 + 0)   + lane * 8);
        short8 b1 = *(const short8*)(w2frag + (tt * 1024 + 512) + lane * 8);
        f32x4 acc = {0.f, 0.f, 0.f, 0.f};
        acc = __builtin_amdgcn_mfma_f32_16x16x32_bf16(a0, b0, acc, 0, 0, 0);
        acc = __builtin_amdgcn_mfma_f32_16x16x32_bf16(a1, b1, acc, 0, 0, 0);
        int o = tt * 16 + m;
        if (o < 64) {
            // p: pack to fp8 e4m3 (rows i, i+1 share a pk convert)
            int pk01 = __builtin_amdgcn_cvt_pk_fp8_f32(acc[0], acc[1], 0, false);
            int pk23 = __builtin_amdgcn_cvt_pk_fp8_f32(acc[2], acc[3], 0, false);
            p8[(base16 + quad * 4 + 0) * 64 + o] = (unsigned char)(pk01 & 0xff);
            p8[(base16 + quad * 4 + 1) * 64 + o] = (unsigned char)((pk01 >> 8) & 0xff);
            p8[(base16 + quad * 4 + 2) * 64 + o] = (unsigned char)(pk23 & 0xff);
            p8[(base16 + quad * 4 + 3) * 64 + o] = (unsigned char)((pk23 >> 8) & 0xff);
        } else {
            int oc = o & 63;
#pragma unroll
            for (int i = 0; i < 4; ++i) {
                int node = base16 + quad * 4 + i;
                q16[node * 64 + oc] = f2bf(acc[i]);
            }
        }
    }
}

// ---- gather (r9 structure, fp8 rows): 4 features/lane via uint load -------
//   h2 = relu(mean_j p_j + b2 + q_i);  gsum[batch] += h2 @ Wout
#define S2_NPW 8
__global__ __launch_bounds__(256, 6) void sage2_kernel(
    const unsigned char* __restrict__ p, const unsigned short* __restrict__ q,
    const int* __restrict__ row_start, const int* __restrict__ deg,
    const int* __restrict__ col, const float* __restrict__ b2,
    const float* __restrict__ Wout, const int* __restrict__ batch,
    float* __restrict__ gsum)
{
    int t = threadIdx.x;
    int wave = t >> 6, lane = t & 63;
    int base_node = (blockIdx.x * 4 + wave) * S2_NPW;   // exact cover
    int c = lane & 15;          // feature quad: features 4c..4c+3
    int g = lane >> 4;          // row group 0..3

    float4 b2v = ((const float4*)b2)[c];
    float4 w01 = ((const float4*)Wout)[c * 2];
    float4 w23 = ((const float4*)Wout)[c * 2 + 1];

    // prefetch per-node metadata + neighbor index rows for all 8 nodes
    int rs[S2_NPW], dgs[S2_NPW], cidx[S2_NPW];
#pragma unroll
    for (int n = 0; n < S2_NPW; ++n) {
        rs[n] = row_start[base_node + n];
        dgs[n] = deg[base_node + n];
    }
#pragma unroll
    for (int n = 0; n < S2_NPW; ++n)
        cidx[n] = (lane < dgs[n]) ? col[rs[n] + lane] : 0;

    for (int n = 0; n < S2_NPW; ++n) {
        int node = base_node + n;
        int dg = dgs[n];
        int dgc = (dg < 64) ? dg : 64;

        // each iteration: 2 loads x 4 rows = 8 rows in flight (256 B each)
        float4 a0 = {0.f,0.f,0.f,0.f}, a1 = {0.f,0.f,0.f,0.f};
        for (int j = 0; j < dgc; j += 8) {
            int jj0 = j + g, jj1 = j + 4 + g;           // < 64 always
            int i0 = __shfl(cidx[n], jj0, 64);
            int i1 = __shfl(cidx[n], jj1, 64);
            unsigned v0 = *(const unsigned*)(p + i0 * 64 + c * 4);
            unsigned v1 = *(const unsigned*)(p + i1 * 64 + c * 4);
            if (jj0 < dgc) {
                a0.x += __builtin_amdgcn_cvt_f32_fp8(v0, 0);
                a0.y += __builtin_amdgcn_cvt_f32_fp8(v0, 1);
                a0.z += __builtin_amdgcn_cvt_f32_fp8(v0, 2);
                a0.w += __builtin_amdgcn_cvt_f32_fp8(v0, 3);
            }
            if (jj1 < dgc) {
                a1.x += __builtin_amdgcn_cvt_f32_fp8(v1, 0);
                a1.y += __builtin_amdgcn_cvt_f32_fp8(v1, 1);
                a1.z += __builtin_amdgcn_cvt_f32_fp8(v1, 2);
                a1.w += __builtin_amdgcn_cvt_f32_fp8(v1, 3);
            }
        }
        for (int k = 64; k < dg; ++k) {                 // deg>64 tail (rare)
            int r = col[rs[n] + k];
            unsigned v = *(const unsigned*)(p + r * 64 + c * 4);
            if (g == 0) {
                a0.x += __builtin_amdgcn_cvt_f32_fp8(v, 0);
                a0.y += __builtin_amdgcn_cvt_f32_fp8(v, 1);
                a0.z += __builtin_amdgcn_cvt_f32_fp8(v, 2);
                a0.w += __builtin_amdgcn_cvt_f32_fp8(v, 3);
            }
        }
        float sx = a0.x + a1.x, sy = a0.y + a1.y, sz = a0.z + a1.z, sw = a0.w + a1.w;
        // combine across the 4 row-groups (lanes {L, L^16, L^32, L^48})
        sx += __shfl_xor(sx, 16, 64); sx += __shfl_xor(sx, 32, 64);
        sy += __shfl_xor(sy, 16, 64); sy += __shfl_xor(sy, 32, 64);
        sz += __shfl_xor(sz, 16, 64); sz += __shfl_xor(sz, 32, 64);
        sw += __shfl_xor(sw, 16, 64); sw += __shfl_xor(sw, 32, 64);

        float inv = 1.0f / fmaxf((float)dg, 1.0f);
        ushort4 qv = *(const ushort4*)(q + node * 64 + c * 4);
        float h0 = fmaxf(sx * inv + b2v.x + bf2f(qv.x), 0.f);
        float h1 = fmaxf(sy * inv + b2v.y + bf2f(qv.y), 0.f);
        float h2 = fmaxf(sz * inv + b2v.z + bf2f(qv.z), 0.f);
        float h3 = fmaxf(sw * inv + b2v.w + bf2f(qv.w), 0.f);

        float p0 = h0 * w01.x + h1 * w01.z + h2 * w23.x + h3 * w23.z;
        float p1 = h0 * w01.y + h1 * w01.w + h2 * w23.y + h3 * w23.w;
        if (g != 0) { p0 = 0.f; p1 = 0.f; }             // groups duplicate
        p0 += __shfl_down(p0, 8, 64);  p1 += __shfl_down(p1, 8, 64);
        p0 += __shfl_down(p0, 4, 64);  p1 += __shfl_down(p1, 4, 64);
        p0 += __shfl_down(p0, 2, 64);  p1 += __shfl_down(p1, 2, 64);
        p0 += __shfl_down(p0, 1, 64);  p1 += __shfl_down(p1, 1, 64);
        if (lane == 0) {
            int grp = batch[node];
            atomicAdd(&gsum[grp * 2 + 0], p0);
            atomicAdd(&gsum[grp * 2 + 1], p1);
        }
    }
}

// ---------------- finalize: out = gsum/cnt + bout ----------------
__global__ __launch_bounds__(256) void finalize_kernel(
    const float* __restrict__ gsum, const int* __restrict__ gstart,
    const float* __restrict__ bout, float* __restrict__ out)
{
    int g = blockIdx.x * 256 + threadIdx.x;
    if (g >= N_GRAPHS) return;
    int cnt = gstart[g + 1] - gstart[g];
    float inv = 1.0f / fmaxf((float)cnt, 1.0f);
    out[g * 2 + 0] = gsum[g * 2 + 0] * inv + bout[0];
    out[g * 2 + 1] = gsum[g * 2 + 1] * inv + bout[1];
}

extern "C" void kernel_launch(void* const* d_in, const int* in_sizes, int n_in,
                              void* d_out, int out_size, void* d_ws, size_t ws_size,
                              hipStream_t stream) {
    const int*   x    = (const int*)  d_in[0];
    const int*   ei   = (const int*)  d_in[1];
    const int*   batch= (const int*)  d_in[2];
    const float* emb  = (const float*)d_in[3];
    const float* W1l  = (const float*)d_in[4];
    const float* b1   = (const float*)d_in[5];
    const float* W1r  = (const float*)d_in[6];
    const float* W2l  = (const float*)d_in[7];
    const float* b2   = (const float*)d_in[8];
    const float* W2r  = (const float*)d_in[9];
    const float* Wout = (const float*)d_in[10];
    const float* bout = (const float*)d_in[11];
    float* out = (float*)d_out;

    const int* src = ei;
    const int* dst = ei + N_EDGES;

    char* ws = (char*)d_ws;
    size_t off = 0;
    unsigned char*  p8     = (unsigned char*) (ws + off); off += (size_t)N_NODES * 64;      // 6.4 MB
    unsigned short* q16    = (unsigned short*)(ws + off); off += (size_t)N_NODES * 64 * 2;  // 12.8 MB
    unsigned short* h1b    = (unsigned short*)(ws + off); off += (size_t)N_NODES * 64 * 2;  // 12.8 MB
    unsigned short* w2frag = (unsigned short*)(ws + off); off += (size_t)8192 * 2;
    float*    embW1l = (float*)   (ws + off); off += (size_t)VOCAB * 64 * 4;
    float*    embW1r = (float*)   (ws + off); off += (size_t)VOCAB * 64 * 4;
    int*      rowst  = (int*)     (ws + off); off += (size_t)N_NODES * 4;
    int*      deg    = (int*)     (ws + off); off += (size_t)N_NODES * 4;
    int*      col    = (int*)     (ws + off); off += (size_t)(NBK * CAP + 256) * 4;
    unsigned* edge8  = (unsigned*)(ws + off); off += (size_t)NBK * CAP * 4;
    int*      cursor = (int*)     (ws + off); off += (size_t)NBK * 4;
    int*      gstart = (int*)     (ws + off); off += (size_t)(N_GRAPHS + 1) * 4;
    float*    gsum   = (float*)   (ws + off); off += (size_t)N_GRAPHS * 2 * 4;

    setup_kernel<<<GB + 32 + 1, 256, 0, stream>>>(
        batch, gstart, emb, W1l, W1r, W2l, W2r, embW1l, embW1r, w2frag,
        cursor, gsum);
    scatter_kernel<<<SCAT_BLOCKS, 256, 0, stream>>>(src, dst, cursor, edge8);
    csr_kernel<<<NBK, 256, 0, stream>>>(edge8, cursor, rowst, deg, col);
    sage1_kernel<<<N_NODES / (4 * S1_NPW), 256, 0, stream>>>(
        x, embW1l, embW1r, b1, rowst, deg, col, h1b);
    mfma_transform_kernel<<<(N_NODES + 63) / 64, 256, 0, stream>>>(
        h1b, w2frag, p8, q16);
    sage2_kernel<<<N_NODES / (4 * S2_NPW), 256, 0, stream>>>(
        p8, q16, rowst, deg, col, b2, Wout, batch, gsum);
    finalize_kernel<<<(N_GRAPHS + 255) / 256, 256, 0, stream>>>(gsum, gstart, bout, out);
}